// Round 7
// baseline (320.514 us; speedup 1.0000x reference)
//
#include <hip/hip_runtime.h>

#define B_     16
#define N_IN_  6250
#define N_OUT_ 25000
#define C_     64
#define S_     9
#define NNZ_   75000
#define GM_    32           // m-rows per gemm block
#define NBLK_G 782          // ceil(N_OUT/GM_)

typedef __bf16 bf16x8 __attribute__((ext_vector_type(8)));
typedef __bf16 bf16x16 __attribute__((ext_vector_type(16)));
typedef float floatx4 __attribute__((ext_vector_type(4)));

__device__ inline void async_copy16(const void* g, void* l) {
    __builtin_amdgcn_global_load_lds(
        (const __attribute__((address_space(1))) void*)g,
        (__attribute__((address_space(3))) void*)l, 16, 0, 0);
}

// ---------------- CSR build ----------------

__global__ void hist_kernel(const int* __restrict__ rows, int* __restrict__ counts, int nnz) {
    int i = blockIdx.x * blockDim.x + threadIdx.x;
    if (i < nnz) atomicAdd(&counts[rows[i]], 1);
}

__global__ void scan1_kernel(const int* __restrict__ counts, int* __restrict__ offsets,
                             int* __restrict__ bsum, int n) {
    __shared__ int wsum[16];
    int t = threadIdx.x;
    int wid = t >> 6, lane = t & 63;
    int i = blockIdx.x * 1024 + t;
    int v = (i < n) ? counts[i] : 0;
    int s = v;
    #pragma unroll
    for (int d = 1; d < 64; d <<= 1) {
        int u = __shfl_up(s, d, 64);
        if (lane >= d) s += u;
    }
    if (lane == 63) wsum[wid] = s;
    __syncthreads();
    if (wid == 0 && lane < 16) {
        int ws = wsum[lane];
        #pragma unroll
        for (int d = 1; d < 16; d <<= 1) {
            int u = __shfl_up(ws, d, 64);
            if (lane >= d) ws += u;
        }
        wsum[lane] = ws;
    }
    __syncthreads();
    int wave_off = (wid == 0) ? 0 : wsum[wid - 1];
    int incl = s + wave_off;
    if (i < n) offsets[i] = incl - v;
    if (t == 1023) bsum[blockIdx.x] = incl;
}

__global__ void scan2_kernel(int* __restrict__ bsum, int* __restrict__ offsets, int nblk, int n) {
    if (threadIdx.x == 0) {
        int t = 0;
        for (int i = 0; i < nblk; ++i) { int v = bsum[i]; bsum[i] = t; t += v; }
        offsets[n] = t;
    }
}

__global__ void scan3_kernel(int* __restrict__ offsets, const int* __restrict__ bsum,
                             int* __restrict__ cursor, int n) {
    int i = blockIdx.x * 1024 + threadIdx.x;
    if (i < n) {
        int o = offsets[i] + bsum[blockIdx.x];
        offsets[i] = o;
        cursor[i] = o;
    }
}

__global__ void fill_kernel(const int* __restrict__ rows, const int* __restrict__ cols,
                            const float* __restrict__ vals, int* __restrict__ cursor,
                            int* __restrict__ ecol, float* __restrict__ eval, int nnz) {
    int i = blockIdx.x * blockDim.x + threadIdx.x;
    if (i < nnz) {
        int p = atomicAdd(&cursor[rows[i]], 1);
        ecol[p] = cols[i];
        eval[p] = vals[i];
    }
}

// ---------------- x -> xT (f32, [n_in][b][c]) ----------------
// Makes each pool gather a CONTIGUOUS 4KB row instead of 16 segments
// strided 1.6MB apart. grid (1563, 16), block 256 = 4 n-rows x 64 c.
__global__ void transx_kernel(const float* __restrict__ x, float* __restrict__ xT) {
    int n = blockIdx.x * 4 + (threadIdx.x >> 6);
    int c = threadIdx.x & 63;
    int b = blockIdx.y;
    if (n < N_IN_)
        xT[(size_t)n * 1024 + b * 64 + c] = x[(size_t)b * N_IN_ * C_ + (size_t)n * C_ + c];
}

// ---------------- pooling (CSR gather), wave-per-row, coalesced ----------------
// grid N_OUT/4 x 256 (4 waves, wave w = row blockIdx*4+w). Per nnz the wave
// reads xT[col] = 4KB contiguous (lane l owns 64B = 16 f32). Row store =
// 2KB contiguous bf16. Numerics identical to the round-2 pool.
__global__ __launch_bounds__(256) void pool_kernel(
        const float* __restrict__ xT, const int* __restrict__ offsets,
        const int* __restrict__ ecol, const float* __restrict__ eval,
        __bf16* __restrict__ pooledT) {
    int t = threadIdx.x;
    int wid = t >> 6, lane = t & 63;
    int row = blockIdx.x * 4 + wid;
    int beg = offsets[row], end = offsets[row + 1];

    floatx4 acc[4] = {};
    int col = 0; float v = 0.f;
    if (beg < end) { col = ecol[beg]; v = eval[beg]; }
    for (int k = beg; k < end; ++k) {
        int col2 = 0; float v2 = 0.f;
        if (k + 1 < end) { col2 = ecol[k + 1]; v2 = eval[k + 1]; }
        const floatx4* xp = reinterpret_cast<const floatx4*>(xT + (size_t)col * 1024 + lane * 16);
        #pragma unroll
        for (int j = 0; j < 4; ++j) acc[j] += xp[j] * v;
        col = col2; v = v2;
    }

    bf16x16 o;
    #pragma unroll
    for (int j = 0; j < 4; ++j) {
        #pragma unroll
        for (int jj = 0; jj < 4; ++jj) o[j * 4 + jj] = (__bf16)acc[j][jj];
    }
    *reinterpret_cast<bf16x16*>(pooledT + (size_t)row * 1024 + lane * 16) = o;
}

// ---------------- W -> WtF (bf16, MFMA-fragment-major) ----------------
// WtF[(kb*64 + n)*8 + j] = W[(kb*8 + j)*64 + n], kb = k/8 in [0,72).
__global__ void convw_kernel(const float* __restrict__ W, __bf16* __restrict__ WtF) {
    int i = blockIdx.x * blockDim.x + threadIdx.x;   // over 72*64*8
    if (i < 72 * 64 * 8) {
        int kb = i >> 9;
        int n  = (i >> 3) & 63;
        int j  = i & 7;
        WtF[i] = (__bf16)W[(kb * 8 + j) * 64 + n];
    }
}

// ---------------- spiral gather + GEMM + bias + ELU (m97 structure) ----------------
// Block = 512 threads (8 waves), owns 32 m-rows x ALL 16 batches x 64 cols.
// Per s-step: stage 32 gathered pooledT rows (64KB) + W[s] slice (8KB) into
// LDS via COALESCED global_load_lds (1KB contiguous per instruction, the
// scatter-fix), double-buffered; wave w computes batches {2w,2w+1}:
// 2b x 2mi x 4nt x 2kc = 32 MFMA/step. A-reads XOR-swizzled (chunk ^ l16),
// staged with inverse-swizzled source (both-sides rule). One barrier/step.
__global__ __launch_bounds__(512, 2) void gemm_kernel(
        const __bf16* __restrict__ pooledT, const int* __restrict__ spiral,
        const __bf16* __restrict__ WtF, const float* __restrict__ bias,
        float* __restrict__ out) {
    __shared__ __bf16 As[2][GM_ * 1024];   // 2 x 64KB
    __shared__ __bf16 Ws[2][4096];         // 2 x 8KB
    __shared__ int spp[GM_][12];           // spiral rows for this tile (pad 9->12)

    int bx = blockIdx.x;
    int mbase = bx * GM_;
    int t = threadIdx.x;
    int wave = t >> 6, lane = t & 63;
    int q = lane >> 4, l16 = lane & 15;

    // tile spiral indices -> LDS (broadcast source for staging)
    if (t < GM_ * S_) {
        int r = t / S_, s = t - r * S_;
        int m = mbase + r;
        int mc = (m < N_OUT_) ? m : (N_OUT_ - 1);
        spp[r][s] = spiral[mc * S_ + s];
    }
    __syncthreads();

    // stage step s into buffer d: A = 4096 x 16B chunks (8/thread), W = 512 (1/thread)
    auto stage = [&](int s, int d) {
        #pragma unroll
        for (int k = 0; k < 8; ++k) {
            int c = t + k * 512;
            int r = c >> 7;            // row 0..31 (uniform per wave)
            int f = c & 127;           // 16B chunk within row
            async_copy16((const char*)pooledT + (size_t)spp[r][s] * 2048
                             + ((f ^ (r & 15)) << 4),
                         (char*)&As[d][0] + ((size_t)c << 4));
        }
        async_copy16((const char*)WtF + (size_t)s * 8192 + ((size_t)t << 4),
                     (char*)&Ws[d][0] + ((size_t)t << 4));
    };

    stage(0, 0);
    __syncthreads();   // vmcnt(0) drain: buffer 0 ready

    floatx4 acc[2][2][4] = {};

    #pragma unroll
    for (int s = 0; s < S_; ++s) {
        int cur = s & 1;
        if (s + 1 < S_) stage(s + 1, cur ^ 1);

        // W fragments: elem = ((kc*4+q)*64 + nt*16 + l16)*8  (proven conflict-free)
        bf16x8 wf[4][2];
        #pragma unroll
        for (int kc = 0; kc < 2; ++kc)
            #pragma unroll
            for (int nt = 0; nt < 4; ++nt)
                wf[nt][kc] = *reinterpret_cast<const bf16x8*>(
                    &Ws[cur][(((kc << 2) + q) << 6 | (nt << 4) | l16) << 3]);

        // A fragments: row r = mi*16+l16, chunk F = bg*8+kc*4+q, read at F^l16
        bf16x8 af[2][2][2];
        #pragma unroll
        for (int bb = 0; bb < 2; ++bb) {
            int bg = 2 * wave + bb;
            #pragma unroll
            for (int mi = 0; mi < 2; ++mi) {
                int r = mi * 16 + l16;
                #pragma unroll
                for (int kc = 0; kc < 2; ++kc) {
                    int F = (bg << 3) + (kc << 2) + q;
                    af[bb][mi][kc] = *reinterpret_cast<const bf16x8*>(
                        &As[cur][(size_t)r * 1024 + ((F ^ l16) << 3)]);
                }
            }
        }

        #pragma unroll
        for (int kc = 0; kc < 2; ++kc)
            #pragma unroll
            for (int nt = 0; nt < 4; ++nt)
                #pragma unroll
                for (int bb = 0; bb < 2; ++bb)
                    #pragma unroll
                    for (int mi = 0; mi < 2; ++mi)
                        acc[bb][mi][nt] = __builtin_amdgcn_mfma_f32_16x16x32_bf16(
                            af[bb][mi][kc], wf[nt][kc], acc[bb][mi][nt], 0, 0, 0);

        __syncthreads();   // drains next-stage loads; buffers swap
    }

    // epilogue: D[m = q*4+i][n = l16] per (bb, mi, nt)
    #pragma unroll
    for (int bb = 0; bb < 2; ++bb) {
        int bg = 2 * wave + bb;
        float* outb = out + (size_t)bg * N_OUT_ * C_;
        #pragma unroll
        for (int mi = 0; mi < 2; ++mi) {
            #pragma unroll
            for (int nt = 0; nt < 4; ++nt) {
                int col = (nt << 4) + l16;
                float bn = bias[col];
                #pragma unroll
                for (int i = 0; i < 4; ++i) {
                    int mm = mbase + mi * 16 + q * 4 + i;
                    if (mm < N_OUT_) {
                        float v = acc[bb][mi][nt][i] + bn;
                        v = (v > 0.0f) ? v : expm1f(v);
                        outb[(size_t)mm * C_ + col] = v;
                    }
                }
            }
        }
    }
}

extern "C" void kernel_launch(void* const* d_in, const int* in_sizes, int n_in,
                              void* d_out, int out_size, void* d_ws, size_t ws_size,
                              hipStream_t stream) {
    const float* x      = (const float*)d_in[0];
    const float* tvals  = (const float*)d_in[1];
    const int*   trow   = (const int*)d_in[2];
    const int*   tcol   = (const int*)d_in[3];
    const int*   spiral = (const int*)d_in[4];
    const float* W      = (const float*)d_in[5];
    const float* bias   = (const float*)d_in[6];
    float* out = (float*)d_out;

    char* ws = (char*)d_ws;
    size_t off = 0;
    auto alloc = [&](size_t bytes) -> void* {
        void* p = ws + off;
        off += (bytes + 255) & ~(size_t)255;
        return p;
    };
    __bf16* pooledT = (__bf16*)alloc((size_t)N_OUT_ * 16 * 64 * 2);   // 51.2 MB
    float*  xT      = (float*)alloc((size_t)N_IN_ * 16 * 64 * 4);     // 25.6 MB
    __bf16* WtF     = (__bf16*)alloc(72 * 64 * 8 * 2);
    int*    cursor  = (int*)alloc(N_OUT_ * 4);
    int*    offsets = (int*)alloc((N_OUT_ + 1) * 4);
    int*    ecol    = (int*)alloc(NNZ_ * 4);
    float*  eval    = (float*)alloc(NNZ_ * 4);
    int*    counts  = (int*)alloc(N_OUT_ * 4);
    int*    bsum    = (int*)alloc(32 * 4);

    const int NBLK = (N_OUT_ + 1023) / 1024;   // 25
    hipMemsetAsync(counts, 0, N_OUT_ * 4, stream);
    hist_kernel<<<(NNZ_ + 255) / 256, 256, 0, stream>>>(trow, counts, NNZ_);
    scan1_kernel<<<NBLK, 1024, 0, stream>>>(counts, offsets, bsum, N_OUT_);
    scan2_kernel<<<1, 64, 0, stream>>>(bsum, offsets, NBLK, N_OUT_);
    scan3_kernel<<<NBLK, 1024, 0, stream>>>(offsets, bsum, cursor, N_OUT_);
    fill_kernel<<<(NNZ_ + 255) / 256, 256, 0, stream>>>(trow, tcol, tvals, cursor, ecol, eval, NNZ_);
    transx_kernel<<<dim3((N_IN_ + 3) / 4, 16), 256, 0, stream>>>(x, xT);
    convw_kernel<<<(72 * 64 * 8 + 255) / 256, 256, 0, stream>>>(W, WtF);
    pool_kernel<<<N_OUT_ / 4, 256, 0, stream>>>(xT, offsets, ecol, eval, pooledT);
    gemm_kernel<<<NBLK_G, 512, 0, stream>>>(pooledT, spiral, WtF, bias, out);
}